// Round 3
// baseline (227.300 us; speedup 1.0000x reference)
//
#include <hip/hip_runtime.h>
#include <hip/hip_bf16.h>

#define B_ 2
#define P_ 100000
#define CIN_ 23
#define C_ 64
#define H_ 512
#define W_ 512
#define S_ (H_*W_)

typedef __attribute__((ext_vector_type(8))) short short8;
typedef __attribute__((ext_vector_type(4))) float f32x4;

__device__ inline unsigned short f2bf(float f) {
    union { __hip_bfloat16 h; unsigned short u; } cv;
    cv.h = __float2bfloat16(f);
    return cv.u;
}
__device__ inline float bf2f(unsigned short u) {
    union { unsigned int i; float f; } cv;
    cv.i = ((unsigned int)u) << 16;
    return cv.f;
}

// ---------------- Stage 1: PointNet (Linear->BN1->ReLU) + scatter-max ----------------
// one thread per (point, channel-pair); packed 2xbf16 CAS-max into grid words
__global__ __launch_bounds__(256) void k_pointnet_scatter(
    const float* __restrict__ feat,
    const int* __restrict__ indices,
    const int* __restrict__ paddings,
    const float* __restrict__ w_pn,
    const float* __restrict__ g1, const float* __restrict__ b1,
    const float* __restrict__ m1, const float* __restrict__ v1,
    unsigned int* __restrict__ grid_w)      // B*S*32 words (2 bf16 channels each)
{
    int t  = blockIdx.x * 256 + threadIdx.x;
    int w  = t & 31;                        // word -> channels 2w, 2w+1
    int pt = t >> 5;
    if (pt >= B_ * P_) return;
    if (paddings[pt] != 0) return;          // padded -> dummy segment (dropped)

    int c0 = w * 2, c1 = c0 + 1;
    const float* f = feat + (size_t)pt * CIN_;
    float a0 = 0.f, a1 = 0.f;
    #pragma unroll
    for (int i = 0; i < CIN_; ++i) {
        float fi = f[i];
        a0 += fi * w_pn[i * C_ + c0];
        a1 += fi * w_pn[i * C_ + c1];
    }
    float s0 = g1[c0] * rsqrtf(v1[c0] + 1e-5f);
    float s1 = g1[c1] * rsqrtf(v1[c1] + 1e-5f);
    float val0 = fmaxf((a0 - m1[c0]) * s0 + b1[c0], 0.f);   // ReLU; mask==1 for valid
    float val1 = fmaxf((a1 - m1[c1]) * s1 + b1[c1], 0.f);
    unsigned int v0 = f2bf(val0);           // non-negative bf16: uint order == float order
    unsigned int v1u = f2bf(val1);

    int b = pt / P_;
    unsigned int* addr = grid_w + ((size_t)b * S_ + (size_t)indices[pt]) * 32 + w;
    unsigned int old = *addr;
    while (true) {
        unsigned int lo = old & 0xffffu, hi = old >> 16;
        unsigned int nlo = lo > v0 ? lo : v0;
        unsigned int nhi = hi > v1u ? hi : v1u;
        unsigned int neu = (nhi << 16) | nlo;
        if (neu == old) break;              // nothing to raise
        unsigned int prev = atomicCAS(addr, old, neu);
        if (prev == old) break;
        old = prev;
    }
}

// ---------------- Stage 2: 1x1 conv (64x64) + BN2 + ReLU, in place, MFMA ----------------
// one wave per 16-voxel tile: C[16,64] = A[16,64] * W^T, K=64, bf16 grid in/out
__global__ __launch_bounds__(256) void k_conv(
    unsigned short* __restrict__ grid,      // bf16
    const float* __restrict__ conv_w,       // [out n][in k] f32
    const float* __restrict__ g2, const float* __restrict__ b2,
    const float* __restrict__ m2, const float* __restrict__ v2)
{
    int lane = threadIdx.x & 63;
    int wid  = (blockIdx.x * 256 + threadIdx.x) >> 6;   // tile id 0..32767
    int row  = lane & 15;       // A-row / B-col / C-col
    int grp  = lane >> 4;       // k-group

    // B fragments: lane holds B[k = ks*32 + grp*8 + j][n = t*16 + row] = W[n][k]
    short8 bfrag[4][2];
    #pragma unroll
    for (int t = 0; t < 4; ++t)
        #pragma unroll
        for (int ks = 0; ks < 2; ++ks) {
            const float* wp = conv_w + (t * 16 + row) * 64 + ks * 32 + grp * 8;
            f32x4 lo = *(const f32x4*)(wp);
            f32x4 hi = *(const f32x4*)(wp + 4);
            short8 v;
            #pragma unroll
            for (int j = 0; j < 4; ++j) {
                v[j]     = (short)f2bf(lo[j]);
                v[j + 4] = (short)f2bf(hi[j]);
            }
            bfrag[t][ks] = v;
        }

    // BN2 scale/shift for this lane's output columns
    float sc[4], sh[4];
    #pragma unroll
    for (int t = 0; t < 4; ++t) {
        int n   = t * 16 + row;
        float s = g2[n] * rsqrtf(v2[n] + 1e-3f);
        sc[t] = s;
        sh[t] = b2[n] - m2[n] * s;
    }

    unsigned short* gp = grid + (size_t)wid * 16 * 64;

    // A fragments: direct bf16 vector loads
    short8 a[2];
    #pragma unroll
    for (int ks = 0; ks < 2; ++ks)
        a[ks] = *(const short8*)(gp + row * 64 + ks * 32 + grp * 8);

    f32x4 acc[4];
    #pragma unroll
    for (int t = 0; t < 4; ++t) acc[t] = (f32x4){0.f, 0.f, 0.f, 0.f};
    #pragma unroll
    for (int t = 0; t < 4; ++t) {
        acc[t] = __builtin_amdgcn_mfma_f32_16x16x32_bf16(a[0], bfrag[t][0], acc[t], 0, 0, 0);
        acc[t] = __builtin_amdgcn_mfma_f32_16x16x32_bf16(a[1], bfrag[t][1], acc[t], 0, 0, 0);
    }

    // epilogue: C[m = grp*4+r][n = t*16+row] (m89-verified mapping), BN2+ReLU, bf16 store
    #pragma unroll
    for (int t = 0; t < 4; ++t)
        #pragma unroll
        for (int r = 0; r < 4; ++r) {
            float val = fmaxf(acc[t][r] * sc[t] + sh[t], 0.f);
            gp[(grp * 4 + r) * 64 + t * 16 + row] = f2bf(val);
        }
}

// ---------------- Stage 3: bilinear gather ----------------
// im[b,x,y] = v[b,y,x] -> voxel id = y*W + x ; one lane per (point, channel)
// OUTPUT IS FLOAT32 (reference output dtype)
__global__ __launch_bounds__(256) void k_gather(
    const unsigned short* __restrict__ grid,   // bf16
    const float* __restrict__ vxyz,
    float* __restrict__ out)
{
    int t  = blockIdx.x * 256 + threadIdx.x;
    int c  = t & 63;
    int pt = t >> 6;
    if (pt >= B_ * P_) return;
    int b = pt / P_;

    float xq = vxyz[(size_t)pt * 3 + 0];
    float yq = vxyz[(size_t)pt * 3 + 1];
    int x0 = (int)floorf(xq); x0 = min(max(x0, 0), W_ - 1);
    int x1 = min(x0 + 1, W_ - 1);
    int y0 = (int)floorf(yq); y0 = min(max(y0, 0), H_ - 1);
    int y1 = min(y0 + 1, H_ - 1);
    float x0f = (float)x0, x1f = (float)x1, y0f = (float)y0, y1f = (float)y1;
    float wa = (x1f - xq) * (y1f - yq);
    float wb = (x1f - xq) * (yq - y0f);
    float wc = (xq - x0f) * (y1f - yq);
    float wd = (xq - x0f) * (yq - y0f);

    const unsigned short* g = grid + (size_t)b * S_ * C_;
    float Ia = bf2f(g[(size_t)(y0 * W_ + x0) * C_ + c]);
    float Ib = bf2f(g[(size_t)(y1 * W_ + x0) * C_ + c]);
    float Ic = bf2f(g[(size_t)(y0 * W_ + x1) * C_ + c]);
    float Id = bf2f(g[(size_t)(y1 * W_ + x1) * C_ + c]);

    out[t] = wa * Ia + wb * Ib + wc * Ic + wd * Id;
}

extern "C" void kernel_launch(void* const* d_in, const int* in_sizes, int n_in,
                              void* d_out, int out_size, void* d_ws, size_t ws_size,
                              hipStream_t stream)
{
    // setup_inputs order:
    // 0 points_xyz (unused), 1 points_feature, 2 points_mask (unused; ==1-paddings),
    // 3 indices, 4 paddings, 5 voxel_xyz, 6 w_pn, 7..10 bn1 g/b/m/v,
    // 11 conv_w, 12..15 bn2 g/b/m/v  — all floats f32, ints int32, OUT f32
    const float* feat     = (const float*)d_in[1];
    const int*   indices  = (const int*)d_in[3];
    const int*   paddings = (const int*)d_in[4];
    const float* vxyz     = (const float*)d_in[5];
    const float* w_pn     = (const float*)d_in[6];
    const float* g1       = (const float*)d_in[7];
    const float* b1       = (const float*)d_in[8];
    const float* m1       = (const float*)d_in[9];
    const float* v1       = (const float*)d_in[10];
    const float* cw       = (const float*)d_in[11];
    const float* g2       = (const float*)d_in[12];
    const float* b2       = (const float*)d_in[13];
    const float* m2       = (const float*)d_in[14];
    const float* v2       = (const float*)d_in[15];

    unsigned int* grid_w = (unsigned int*)d_ws;        // B*S*C bf16 = 67 MB
    size_t gbytes = (size_t)B_ * S_ * C_ * sizeof(unsigned short);
    hipMemsetAsync(grid_w, 0, gbytes, stream);

    k_pointnet_scatter<<<(B_ * P_ * 32) / 256, 256, 0, stream>>>(
        feat, indices, paddings, w_pn, g1, b1, m1, v1, grid_w);

    k_conv<<<((B_ * S_ / 16) * 64) / 256, 256, 0, stream>>>(
        (unsigned short*)d_ws, cw, g2, b2, m2, v2);

    k_gather<<<(B_ * P_ * C_) / 256, 256, 0, stream>>>(
        (const unsigned short*)d_ws, vxyz, (float*)d_out);
}

// Round 4
// 156.518 us; speedup vs baseline: 1.4522x; 1.4522x over previous
//
#include <hip/hip_runtime.h>
#include <hip/hip_bf16.h>

#define B_ 2
#define P_ 100000
#define CIN_ 23
#define C_ 64
#define H_ 512
#define W_ 512
#define S_ (H_*W_)       // 262144 = 1<<18
#define NPT_ (B_*P_)     // 200000
#define NVOX_ (B_*S_)    // 524288

typedef __attribute__((ext_vector_type(8))) short short8;
typedef __attribute__((ext_vector_type(4))) float f32x4;

__device__ inline unsigned short f2bf(float f) {
    union { __hip_bfloat16 h; unsigned short u; } cv;
    cv.h = __float2bfloat16(f);
    return cv.u;
}
__device__ inline float bf2f(unsigned short u) {
    union { unsigned int i; float f; } cv;
    cv.i = ((unsigned int)u) << 16;
    return cv.f;
}

// ---------------- Stage 1a: build per-voxel linked lists ----------------
// one thread per point: head[v] <- pt, next[pt] <- old head
__global__ __launch_bounds__(256) void k_fill(
    const int* __restrict__ indices,
    const int* __restrict__ paddings,
    int* __restrict__ head,
    int* __restrict__ next)
{
    int pt = blockIdx.x * 256 + threadIdx.x;
    if (pt >= NPT_) return;
    if (paddings[pt] != 0) return;              // padded -> dropped
    int v = (pt / P_) * S_ + indices[pt];
    int old = atomicExch(&head[v], pt);
    next[pt] = old;
}

// ---------------- Stage 1b: per-voxel PointNet + max-reduce ----------------
// one wave per voxel, lane = channel. BN1 scale > 0 => max-then-BN == BN-then-max.
// Writes the ENTIRE grid (zeros for empty voxels) -> replaces memset.
__global__ __launch_bounds__(256) void k_voxel(
    const float* __restrict__ feat,
    const int* __restrict__ head,
    const int* __restrict__ next,
    const float* __restrict__ w_pn,
    const float* __restrict__ g1, const float* __restrict__ b1,
    const float* __restrict__ m1, const float* __restrict__ v1,
    unsigned short* __restrict__ grid)          // bf16 [NVOX_][C_]
{
    int lane = threadIdx.x & 63;
    int v = (blockIdx.x * 256 + threadIdx.x) >> 6;
    if (v >= NVOX_) return;

    unsigned short* row = grid + (size_t)v * C_ + lane;
    int pt = __builtin_amdgcn_readfirstlane(head[v]);
    if (pt < 0) { *row = 0; return; }           // empty voxel -> exact 0

    // per-channel PointNet weights held in VGPRs for the whole walk
    float w[CIN_];
    #pragma unroll
    for (int i = 0; i < CIN_; ++i) w[i] = w_pn[i * C_ + lane];

    float mx = -1e30f;
    while (pt >= 0) {
        const float* f = feat + (size_t)pt * CIN_;   // wave-uniform -> scalar loads
        float a = 0.f;
        #pragma unroll
        for (int i = 0; i < CIN_; ++i) a += f[i] * w[i];
        mx = fmaxf(mx, a);
        pt = __builtin_amdgcn_readfirstlane(next[pt]);
    }
    float s   = g1[lane] * rsqrtf(v1[lane] + 1e-5f);
    float val = fmaxf((mx - m1[lane]) * s + b1[lane], 0.f);
    *row = f2bf(val);
}

// ---------------- Stage 2: 1x1 conv (64x64) + BN2 + ReLU, in place, MFMA ----------------
// one wave per FOUR 16-voxel tiles (B-fragments + BN amortized 4x)
__global__ __launch_bounds__(256) void k_conv(
    unsigned short* __restrict__ grid,      // bf16
    const float* __restrict__ conv_w,       // [out n][in k] f32
    const float* __restrict__ g2, const float* __restrict__ b2,
    const float* __restrict__ m2, const float* __restrict__ v2)
{
    int lane = threadIdx.x & 63;
    int wv   = (blockIdx.x * 256 + threadIdx.x) >> 6;   // 0..8191
    int row  = lane & 15;       // A-row / B-col / C-col
    int grp  = lane >> 4;       // k-group

    // B fragments: lane holds B[k = ks*32 + grp*8 + j][n = t*16 + row] = W[n][k]
    short8 bfrag[4][2];
    #pragma unroll
    for (int t = 0; t < 4; ++t)
        #pragma unroll
        for (int ks = 0; ks < 2; ++ks) {
            const float* wp = conv_w + (t * 16 + row) * 64 + ks * 32 + grp * 8;
            f32x4 lo = *(const f32x4*)(wp);
            f32x4 hi = *(const f32x4*)(wp + 4);
            short8 vv;
            #pragma unroll
            for (int j = 0; j < 4; ++j) {
                vv[j]     = (short)f2bf(lo[j]);
                vv[j + 4] = (short)f2bf(hi[j]);
            }
            bfrag[t][ks] = vv;
        }

    // BN2 scale/shift for this lane's output columns
    float sc[4], sh[4];
    #pragma unroll
    for (int t = 0; t < 4; ++t) {
        int n   = t * 16 + row;
        float s = g2[n] * rsqrtf(v2[n] + 1e-3f);
        sc[t] = s;
        sh[t] = b2[n] - m2[n] * s;
    }

    #pragma unroll
    for (int sub = 0; sub < 4; ++sub) {
        unsigned short* gp = grid + ((size_t)wv * 4 + sub) * 16 * 64;

        // A fragments: direct bf16 vector loads (wave reads full tile before storing)
        short8 a[2];
        #pragma unroll
        for (int ks = 0; ks < 2; ++ks)
            a[ks] = *(const short8*)(gp + row * 64 + ks * 32 + grp * 8);

        f32x4 acc[4];
        #pragma unroll
        for (int t = 0; t < 4; ++t) acc[t] = (f32x4){0.f, 0.f, 0.f, 0.f};
        #pragma unroll
        for (int t = 0; t < 4; ++t) {
            acc[t] = __builtin_amdgcn_mfma_f32_16x16x32_bf16(a[0], bfrag[t][0], acc[t], 0, 0, 0);
            acc[t] = __builtin_amdgcn_mfma_f32_16x16x32_bf16(a[1], bfrag[t][1], acc[t], 0, 0, 0);
        }

        // epilogue: C[m = grp*4+r][n = t*16+row], BN2+ReLU, bf16 store in place
        #pragma unroll
        for (int t = 0; t < 4; ++t)
            #pragma unroll
            for (int r = 0; r < 4; ++r) {
                float val = fmaxf(acc[t][r] * sc[t] + sh[t], 0.f);
                gp[(grp * 4 + r) * 64 + t * 16 + row] = f2bf(val);
            }
    }
}

// ---------------- Stage 3: bilinear gather ----------------
// im[b,x,y] = v[b,y,x] -> voxel id = y*W + x ; one lane per (point, channel)
__global__ __launch_bounds__(256) void k_gather(
    const unsigned short* __restrict__ grid,   // bf16
    const float* __restrict__ vxyz,
    float* __restrict__ out)                   // f32 output
{
    int t  = blockIdx.x * 256 + threadIdx.x;
    int c  = t & 63;
    int pt = t >> 6;
    if (pt >= NPT_) return;
    int b = pt / P_;

    float xq = vxyz[(size_t)pt * 3 + 0];
    float yq = vxyz[(size_t)pt * 3 + 1];
    int x0 = (int)floorf(xq); x0 = min(max(x0, 0), W_ - 1);
    int x1 = min(x0 + 1, W_ - 1);
    int y0 = (int)floorf(yq); y0 = min(max(y0, 0), H_ - 1);
    int y1 = min(y0 + 1, H_ - 1);
    float x0f = (float)x0, x1f = (float)x1, y0f = (float)y0, y1f = (float)y1;
    float wa = (x1f - xq) * (y1f - yq);
    float wb = (x1f - xq) * (yq - y0f);
    float wc = (xq - x0f) * (y1f - yq);
    float wd = (xq - x0f) * (yq - y0f);

    const unsigned short* g = grid + (size_t)b * S_ * C_;
    float Ia = bf2f(g[(size_t)(y0 * W_ + x0) * C_ + c]);
    float Ib = bf2f(g[(size_t)(y1 * W_ + x0) * C_ + c]);
    float Ic = bf2f(g[(size_t)(y0 * W_ + x1) * C_ + c]);
    float Id = bf2f(g[(size_t)(y1 * W_ + x1) * C_ + c]);

    out[t] = wa * Ia + wb * Ib + wc * Ic + wd * Id;
}

extern "C" void kernel_launch(void* const* d_in, const int* in_sizes, int n_in,
                              void* d_out, int out_size, void* d_ws, size_t ws_size,
                              hipStream_t stream)
{
    const float* feat     = (const float*)d_in[1];
    const int*   indices  = (const int*)d_in[3];
    const int*   paddings = (const int*)d_in[4];
    const float* vxyz     = (const float*)d_in[5];
    const float* w_pn     = (const float*)d_in[6];
    const float* g1       = (const float*)d_in[7];
    const float* b1       = (const float*)d_in[8];
    const float* m1       = (const float*)d_in[9];
    const float* v1       = (const float*)d_in[10];
    const float* cw       = (const float*)d_in[11];
    const float* g2       = (const float*)d_in[12];
    const float* b2       = (const float*)d_in[13];
    const float* m2       = (const float*)d_in[14];
    const float* v2       = (const float*)d_in[15];

    // ws layout: grid bf16 (67.1 MB) | head (2.1 MB) | next (0.8 MB)
    unsigned short* grid = (unsigned short*)d_ws;
    int* head = (int*)((char*)d_ws + (size_t)NVOX_ * C_ * sizeof(unsigned short));
    int* next = head + NVOX_;

    hipMemsetAsync(head, 0xFF, (size_t)NVOX_ * sizeof(int), stream);   // head = -1

    k_fill<<<(NPT_ + 255) / 256, 256, 0, stream>>>(indices, paddings, head, next);

    k_voxel<<<(NVOX_ * 64) / 256, 256, 0, stream>>>(
        feat, head, next, w_pn, g1, b1, m1, v1, grid);

    k_conv<<<(NVOX_ / 16 / 4) * 64 / 256, 256, 0, stream>>>(
        grid, cw, g2, b2, m2, v2);

    k_gather<<<(NPT_ * C_) / 256, 256, 0, stream>>>(grid, vxyz, (float*)d_out);
}